// Round 5
// baseline (320.757 us; speedup 1.0000x reference)
//
#include <hip/hip_runtime.h>
#include <math.h>

#define N_NODES 100000
#define N_EDGES 1600000
#define F_IN 165
#define KPAD 192
#define NEG 0.2f
#define NB 98            // ceil(N_NODES / 1024) scan blocks
#define NXCD 8
#define RSZ 12500        // N_NODES / NXCD, exact
#define EPB 1024         // edges per block-chunk (256 thr x 4)
#define NCHUNK ((N_EDGES + EPB - 1) / EPB)

typedef __attribute__((ext_vector_type(8))) short short8v;
typedef __attribute__((ext_vector_type(4))) float f32x4;

static __device__ __forceinline__ unsigned short f2bf(float f) {
    unsigned int u = __float_as_uint(f);
    unsigned int r = (u + 0x7FFFu + ((u >> 16) & 1u)) >> 16;
    return (unsigned short)r;
}
static __device__ __forceinline__ float bf2f(unsigned short b) {
    return __uint_as_float((unsigned int)b << 16);
}

// ---------------- W1 -> transposed bf16 hi/lo [64 cols][192 k] ----------------
__global__ __launch_bounds__(256) void k_wconv(const float* __restrict__ W1,
                                               unsigned short* __restrict__ Wth,
                                               unsigned short* __restrict__ Wtl) {
    int i = blockIdx.x * 256 + threadIdx.x;
    if (i >= 64 * KPAD) return;
    int col = i / KPAD, k = i % KPAD;
    float f = (k < F_IN) ? W1[k * 64 + col] : 0.f;
    unsigned short hi = f2bf(f);
    Wth[i] = hi;
    Wtl[i] = f2bf(f - bf2f(hi));
}

// ---------------- K1: h1 = x @ W1 via bf16 MFMA (hi/lo split), fused alpha ----------------
// block: 256 thr = 4 waves; 64 rows x 64 cols. wave w: rows [w*16, w*16+16).
// A-frag: lane holds x[row = l&15][k = (l>>4)*8 + j]; B-frag: W[k][col = l&15].
// C/D: col = l&15, row = (l>>4)*4 + reg (verified layout).
__global__ __launch_bounds__(256) void k_gemm1(const float* __restrict__ x,
                                               const unsigned short* __restrict__ Wth,
                                               const unsigned short* __restrict__ Wtl,
                                               const float* __restrict__ a_src1,
                                               const float* __restrict__ a_dst1,
                                               float* __restrict__ h1,
                                               float* __restrict__ as1,
                                               float* __restrict__ ad1) {
    __shared__ __align__(16) unsigned short xh[64 * 40];  // 32 k + 8 pad per row
    __shared__ __align__(16) unsigned short xl[64 * 40];
    const int t = threadIdx.x;
    const int w = t >> 6, lane = t & 63;
    const int base = blockIdx.x * 64;
    const int lrow = lane & 15, lk = lane >> 4;

    f32x4 acc[4] = {};

    for (int k0 = 0; k0 < KPAD; k0 += 32) {
        __syncthreads();
        #pragma unroll
        for (int i = t; i < 2048; i += 256) {
            int r = i >> 5, kk = i & 31;
            int row = base + r, k = k0 + kk;
            float f = (row < N_NODES && k < F_IN) ? x[row * F_IN + k] : 0.f;
            unsigned short hi = f2bf(f);
            xh[r * 40 + kk] = hi;
            xl[r * 40 + kk] = f2bf(f - bf2f(hi));
        }
        __syncthreads();
        int arow = w * 16 + lrow;
        short8v a_h = *(const short8v*)(xh + arow * 40 + lk * 8);
        short8v a_l = *(const short8v*)(xl + arow * 40 + lk * 8);
        #pragma unroll
        for (int ct = 0; ct < 4; ++ct) {
            int c = ct * 16 + lrow;
            const short8v b_h = *(const short8v*)(Wth + c * KPAD + k0 + lk * 8);
            const short8v b_l = *(const short8v*)(Wtl + c * KPAD + k0 + lk * 8);
            acc[ct] = __builtin_amdgcn_mfma_f32_16x16x32_bf16(a_h, b_h, acc[ct], 0, 0, 0);
            acc[ct] = __builtin_amdgcn_mfma_f32_16x16x32_bf16(a_h, b_l, acc[ct], 0, 0, 0);
            acc[ct] = __builtin_amdgcn_mfma_f32_16x16x32_bf16(a_l, b_h, acc[ct], 0, 0, 0);
        }
    }

    // epilogue: h1 store + fused per-head alpha reductions
    #pragma unroll
    for (int ct = 0; ct < 4; ++ct) {
        int colbase = ct * 16 + lrow;
        float av = a_src1[colbase], dv = a_dst1[colbase];
        #pragma unroll
        for (int r = 0; r < 4; ++r) {
            int row = base + w * 16 + lk * 4 + r;
            float v = acc[ct][r];
            if (row < N_NODES) h1[row * 64 + colbase] = v;
            float ps = v * av, pd = v * dv;
            ps += __shfl_xor(ps, 1); ps += __shfl_xor(ps, 2); ps += __shfl_xor(ps, 4);
            pd += __shfl_xor(pd, 1); pd += __shfl_xor(pd, 2); pd += __shfl_xor(pd, 4);
            if ((lane & 7) == 0 && row < N_NODES) {
                int head = ct * 2 + (lrow >> 3);
                as1[row * 8 + head] = ps;
                ad1[row * 8 + head] = pd;
            }
        }
    }
}

// ---------------- CSR build, XCD-range-partitioned ----------------
__global__ __launch_bounds__(256) void k_hist(const int* __restrict__ ei,
                                              int* __restrict__ deg) {
    int r = blockIdx.x & (NXCD - 1);
    int chunk = blockIdx.x >> 3;
    int lo = r * RSZ;
    long e0 = (long)chunk * EPB + threadIdx.x * 4;
    if (e0 >= N_EDGES) return;
    int4 d4 = *(const int4*)(ei + N_EDGES + e0);
    #pragma unroll
    for (int k = 0; k < 4; ++k) {
        int d = (&d4.x)[k];
        if ((unsigned)(d - lo) < RSZ) atomicAdd(&deg[d], 1);
    }
}

__global__ __launch_bounds__(256) void k_scan_a(const int* __restrict__ deg,
                                                int* __restrict__ S,
                                                int* __restrict__ blockSum) {
    __shared__ int lds[256];
    int t = threadIdx.x;
    int base = blockIdx.x * 1024 + t * 4;
    int v[4]; int sum = 0;
    #pragma unroll
    for (int k = 0; k < 4; ++k) { int i = base + k; v[k] = (i < N_NODES) ? deg[i] : 0; sum += v[k]; }
    lds[t] = sum; __syncthreads();
    for (int off = 1; off < 256; off <<= 1) {
        int x = lds[t];
        int y = (t >= off) ? lds[t - off] : 0;
        __syncthreads();
        lds[t] = x + y;
        __syncthreads();
    }
    int run = lds[t] - sum;
    #pragma unroll
    for (int k = 0; k < 4; ++k) {
        run += v[k];
        int i = base + k;
        if (i < N_NODES) S[i] = run;
    }
    if (t == 255) blockSum[blockIdx.x] = lds[255];
}

__global__ __launch_bounds__(256) void k_scan_b(const int* __restrict__ blockSum,
                                                int* __restrict__ blockOff) {
    __shared__ int lds[256];
    int t = threadIdx.x;
    int v = (t < NB) ? blockSum[t] : 0;
    lds[t] = v; __syncthreads();
    for (int off = 1; off < 256; off <<= 1) {
        int x = lds[t];
        int y = (t >= off) ? lds[t - off] : 0;
        __syncthreads();
        lds[t] = x + y;
        __syncthreads();
    }
    if (t < NB) blockOff[t] = lds[t] - v;
}

__global__ __launch_bounds__(256) void k_scan_c(int* __restrict__ S,
                                                const int* __restrict__ deg,
                                                const int* __restrict__ blockOff,
                                                int* __restrict__ cursor) {
    int i = blockIdx.x * 256 + threadIdx.x;
    if (i < N_NODES) {
        int s = S[i] + blockOff[i >> 10];
        S[i] = s;
        cursor[i] = s - deg[i];
    }
}

__global__ __launch_bounds__(256) void k_scatter(const int* __restrict__ ei,
                                                 int* __restrict__ cursor,
                                                 int* __restrict__ ssrc) {
    int r = blockIdx.x & (NXCD - 1);
    int chunk = blockIdx.x >> 3;
    int lo = r * RSZ;
    long e0 = (long)chunk * EPB + threadIdx.x * 4;
    if (e0 >= N_EDGES) return;
    int4 s4 = *(const int4*)(ei + e0);
    int4 d4 = *(const int4*)(ei + N_EDGES + e0);
    #pragma unroll
    for (int k = 0; k < 4; ++k) {
        int d = (&d4.x)[k];
        if ((unsigned)(d - lo) < RSZ) {
            int pos = atomicAdd(&cursor[d], 1);
            ssrc[pos] = (&s4.x)[k];
        }
    }
}

// ---------------- layer-1 aggregate + elu + @W2 + alpha2, fused ----------------
__global__ __launch_bounds__(256) void k_agg1(const int* __restrict__ ssrc,
                                              const int* __restrict__ S,
                                              const int* __restrict__ deg,
                                              const float* __restrict__ h1,
                                              const float* __restrict__ as1,
                                              const float* __restrict__ ad1,
                                              const float* __restrict__ b1,
                                              const float* __restrict__ W2,
                                              const float* __restrict__ a_src2,
                                              const float* __restrict__ a_dst2,
                                              float4* __restrict__ pk2) {
    int node = blockIdx.x * 4 + (threadIdx.x >> 6);
    int lane = threadIdx.x & 63;
    if (node >= N_NODES) return;
    int h = lane >> 3;
    int end = S[node], start = end - deg[node];
    float adh = ad1[node * 8 + h];
    float ev = as1[node * 8 + h] + adh;
    ev = fmaxf(ev, NEG * ev);
    float w = __expf(ev);
    float acc = w * h1[node * 64 + lane];
    float z = w;

    for (int c = start; c < end; c += 64) {
        int cnt = end - c; if (cnt > 64) cnt = 64;
        int sidx = (lane < cnt) ? ssrc[c + lane] : 0;
        int k = 0;
        for (; k + 4 <= cnt; k += 4) {
            int s0 = __shfl(sidx, k);
            int s1 = __shfl(sidx, k + 1);
            int s2 = __shfl(sidx, k + 2);
            int s3 = __shfl(sidx, k + 3);
            float a0 = as1[s0 * 8 + h];
            float a1 = as1[s1 * 8 + h];
            float a2 = as1[s2 * 8 + h];
            float a3 = as1[s3 * 8 + h];
            float g0 = h1[s0 * 64 + lane];
            float g1 = h1[s1 * 64 + lane];
            float g2 = h1[s2 * 64 + lane];
            float g3 = h1[s3 * 64 + lane];
            float e0 = a0 + adh; e0 = fmaxf(e0, NEG * e0); float w0 = __expf(e0);
            float e1 = a1 + adh; e1 = fmaxf(e1, NEG * e1); float w1 = __expf(e1);
            float e2 = a2 + adh; e2 = fmaxf(e2, NEG * e2); float w2 = __expf(e2);
            float e3 = a3 + adh; e3 = fmaxf(e3, NEG * e3); float w3 = __expf(e3);
            acc = fmaf(w0, g0, acc); acc = fmaf(w1, g1, acc);
            acc = fmaf(w2, g2, acc); acc = fmaf(w3, g3, acc);
            z += (w0 + w1) + (w2 + w3);
        }
        for (; k < cnt; ++k) {
            int s = __shfl(sidx, k);
            float a = as1[s * 8 + h];
            float g = h1[s * 64 + lane];
            float e2 = a + adh; e2 = fmaxf(e2, NEG * e2);
            float ww = __expf(e2);
            acc = fmaf(ww, g, acc);
            z += ww;
        }
    }

    float o = acc / z + b1[lane];
    o = o > 0.f ? o : expm1f(o);
    float p0 = o * W2[lane * 2 + 0];
    float p1 = o * W2[lane * 2 + 1];
    #pragma unroll
    for (int m = 1; m < 64; m <<= 1) { p0 += __shfl_xor(p0, m); p1 += __shfl_xor(p1, m); }
    if (lane == 0) {
        pk2[node] = make_float4(p0, p1,
                                p0 * a_src2[0] + p1 * a_src2[1],
                                p0 * a_dst2[0] + p1 * a_dst2[1]);
    }
}

// ---------------- layer-2 aggregate + log_softmax, fused ----------------
__global__ __launch_bounds__(256) void k_agg2(const int* __restrict__ ssrc,
                                              const int* __restrict__ S,
                                              const int* __restrict__ deg,
                                              const float4* __restrict__ pk2,
                                              const float* __restrict__ b2,
                                              float* __restrict__ out) {
    int node = blockIdx.x * 16 + (threadIdx.x >> 4);
    int j = threadIdx.x & 15;
    if (node >= N_NODES) return;
    int end = S[node], start = end - deg[node];
    float4 self = pk2[node];
    float ad = self.w;
    float acc0 = 0.f, acc1 = 0.f, z = 0.f;
    if (j == 0) {
        float ev = self.z + ad;
        ev = fmaxf(ev, NEG * ev);
        float w = __expf(ev);
        acc0 = w * self.x; acc1 = w * self.y; z = w;
    }
    int i = start + j;
    for (; i + 16 < end; i += 32) {
        int s0 = ssrc[i], s1 = ssrc[i + 16];
        float4 q0 = pk2[s0], q1 = pk2[s1];
        float e0 = q0.z + ad; e0 = fmaxf(e0, NEG * e0); float w0 = __expf(e0);
        float e1 = q1.z + ad; e1 = fmaxf(e1, NEG * e1); float w1 = __expf(e1);
        acc0 = fmaf(w0, q0.x, acc0); acc0 = fmaf(w1, q1.x, acc0);
        acc1 = fmaf(w0, q0.y, acc1); acc1 = fmaf(w1, q1.y, acc1);
        z += w0 + w1;
    }
    if (i < end) {
        int s = ssrc[i];
        float4 q = pk2[s];
        float e0 = q.z + ad; e0 = fmaxf(e0, NEG * e0); float w0 = __expf(e0);
        acc0 = fmaf(w0, q.x, acc0);
        acc1 = fmaf(w0, q.y, acc1);
        z += w0;
    }
    #pragma unroll
    for (int m = 1; m < 16; m <<= 1) {
        acc0 += __shfl_xor(acc0, m);
        acc1 += __shfl_xor(acc1, m);
        z    += __shfl_xor(z, m);
    }
    if (j == 0) {
        float v0 = acc0 / z + b2[0];
        float v1 = acc1 / z + b2[1];
        float m = fmaxf(v0, v1);
        float lse = m + logf(__expf(v0 - m) + __expf(v1 - m));
        out[node * 2 + 0] = v0 - lse;
        out[node * 2 + 1] = v1 - lse;
    }
}

extern "C" void kernel_launch(void* const* d_in, const int* in_sizes, int n_in,
                              void* d_out, int out_size, void* d_ws, size_t ws_size,
                              hipStream_t stream) {
    const float* x      = (const float*)d_in[0];
    const int*   ei     = (const int*)d_in[1];
    const float* W1     = (const float*)d_in[2];
    const float* a_src1 = (const float*)d_in[3];
    const float* a_dst1 = (const float*)d_in[4];
    const float* b1     = (const float*)d_in[5];
    const float* W2     = (const float*)d_in[6];
    const float* a_src2 = (const float*)d_in[7];
    const float* a_dst2 = (const float*)d_in[8];
    const float* b2     = (const float*)d_in[9];
    float* out = (float*)d_out;

    float* p = (float*)d_ws;
    float* h1   = p; p += N_NODES * 64;
    float* as1  = p; p += N_NODES * 8;
    float* ad1  = p; p += N_NODES * 8;
    float4* pk2 = (float4*)p; p += N_NODES * 4;
    int* ip = (int*)p;
    int* deg      = ip; ip += N_NODES;
    int* S        = ip; ip += N_NODES;
    int* cursor   = ip; ip += N_NODES;
    int* blockSum = ip; ip += 256;
    int* blockOff = ip; ip += 256;
    int* ssrc     = ip; ip += N_EDGES;
    unsigned short* Wth = (unsigned short*)(ip); // 16B-aligned (int section is)
    unsigned short* Wtl = Wth + 64 * KPAD;

    hipMemsetAsync(deg, 0, N_NODES * sizeof(int), stream);

    // CSR build (XCD-range-partitioned hist & scatter)
    k_hist<<<NCHUNK * NXCD, 256, 0, stream>>>(ei, deg);
    k_scan_a<<<NB, 256, 0, stream>>>(deg, S, blockSum);
    k_scan_b<<<1, 256, 0, stream>>>(blockSum, blockOff);
    k_scan_c<<<(N_NODES + 255) / 256, 256, 0, stream>>>(S, deg, blockOff, cursor);
    k_scatter<<<NCHUNK * NXCD, 256, 0, stream>>>(ei, cursor, ssrc);

    // layer 1 (MFMA gemm fused with alpha)
    k_wconv<<<(64 * KPAD + 255) / 256, 256, 0, stream>>>(W1, Wth, Wtl);
    k_gemm1<<<(N_NODES + 63) / 64, 256, 0, stream>>>(x, Wth, Wtl, a_src1, a_dst1, h1, as1, ad1);
    k_agg1<<<(N_NODES + 3) / 4, 256, 0, stream>>>(ssrc, S, deg, h1, as1, ad1, b1, W2,
                                                  a_src2, a_dst2, pk2);
    // layer 2 + log_softmax
    k_agg2<<<(N_NODES + 15) / 16, 256, 0, stream>>>(ssrc, S, deg, pk2, b2, out);
}